// Round 2
// baseline (194.996 us; speedup 1.0000x reference)
//
#include <hip/hip_runtime.h>

// RoDAlignMax: features [4,256,64,64] f32, rois [2048,5] f32 -> out [2048,256,9,9] f32
// Sampling grid is exactly (7i,7j) (63/9 == 7.0 in fp32), so bilinear degenerates
// to a pure gather; masked (inside-ROI) samples become 0 before the 2x2/s1 maxpool.
//
// K1: gather+transpose  G2[b][c][p]  (p = i*10+j, 100 pts, p-fastest) = F[b,c,7i,7j]
//     400 KB -> L2-resident.
// K2: block = one roi, 256 threads, NO LDS. Thread k-loop walks flat output
//     elements el = tid + 256k (perfectly coalesced dword stores), derives
//     (c,q,i,j) incrementally, loads the 2x2 window from G2 (4 dwords, one base
//     address, L1-cached), applies block-uniform ROI bitmasks via cndmask+fmax.

#define NC 256
#define NR 2048

__global__ __launch_bounds__(128) void rod_gather2(const float* __restrict__ F,
                                                   float* __restrict__ G2) {
    int bc = blockIdx.x;                 // b*256 + c, 0..1023
    int t  = threadIdx.x;                // active t < 100
    if (t < 100) {
        int i = (t * 205) >> 11;         // t/10  (valid for t<1024)
        int j = t - 10 * i;              // t%10
        // F[((b*256+c)*64 + 7i)*64 + 7j]; i==9 -> row 63 == reference h0=62,hr=1
        G2[bc * 100 + t] = F[(bc << 12) + i * 448 + j * 7];
    }
}

__global__ __launch_bounds__(256, 4) void rod_main2(const float* __restrict__ G2,
                                                    const float* __restrict__ rois,
                                                    float* __restrict__ out) {
    const int tid = threadIdx.x;
    const int r   = blockIdx.x;

    const float x1 = rois[r * 5 + 1] * 0.25f;
    const float y1 = rois[r * 5 + 2] * 0.25f;
    const float x2 = rois[r * 5 + 3] * 0.25f;
    const float y2 = rois[r * 5 + 4] * 0.25f;
    const int   b  = (int)rois[r * 5 + 0];

    // Block-uniform 10-bit in-ROI masks (grid coord s = 7t is exact).
    unsigned inhM = 0u, inwM = 0u;
    #pragma unroll
    for (int t = 0; t < 10; ++t) {
        float s = 7.0f * (float)t;
        if ((s >= y1) && (s <= y2)) inhM |= (1u << t);
        if ((s >= x1) && (s <= x2)) inwM |= (1u << t);
    }

    const float* Gb  = G2 + b * 25600;          // b*256*100
    float*       dst = out + (size_t)r * 20736; // r*256*81

    // el = c*81 + q starts at tid, advances by 256 per iteration.
    int c = (tid * 405) >> 15;                  // tid/81 (valid for tid<256)
    int q = tid - 81 * c;

    #pragma unroll 4
    for (int k = 0; k < 81; ++k) {
        int i = (q * 57) >> 9;                  // q/9 (valid for q<=80)
        int j = q - 9 * i;

        const float* gp = Gb + c * 100 + i * 10 + j;
        float v00 = gp[0];
        float v01 = gp[1];
        float v10 = gp[10];
        float v11 = gp[11];

        unsigned hb = inhM >> i;                // bits: i, i+1
        unsigned wb = inwM >> j;                // bits: j, j+1
        float a00 = ((hb        & wb       ) & 1u) ? 0.0f : v00;
        float a01 = ((hb        & (wb >> 1)) & 1u) ? 0.0f : v01;
        float a10 = (((hb >> 1) & wb       ) & 1u) ? 0.0f : v10;
        float a11 = (((hb >> 1) & (wb >> 1)) & 1u) ? 0.0f : v11;

        dst[tid + (k << 8)] = fmaxf(fmaxf(a00, a01), fmaxf(a10, a11));

        q += 13; c += 3;                        // el += 256
        if (q >= 81) { q -= 81; c += 1; }
    }
}

extern "C" void kernel_launch(void* const* d_in, const int* in_sizes, int n_in,
                              void* d_out, int out_size, void* d_ws, size_t ws_size,
                              hipStream_t stream) {
    const float* F    = (const float*)d_in[0];   // 4*256*64*64
    const float* rois = (const float*)d_in[1];   // 2048*5
    float*       out  = (float*)d_out;           // 2048*256*81
    float*       G2   = (float*)d_ws;            // 1024*100 floats = 409600 B

    rod_gather2<<<dim3(1024), dim3(128), 0, stream>>>(F, G2);
    rod_main2<<<dim3(NR), dim3(256), 0, stream>>>(G2, rois, out);
}